// Round 1
// baseline (172.680 us; speedup 1.0000x reference)
//
#include <hip/hip_runtime.h>
#include <math.h>

#define B_N 4096
#define C_N 100
#define D_N 384
#define EPSF 1e-12f
#define TILE_R 16
#define PADD 388   // 384 + 4: keeps float4 alignment, breaks bank aliasing

// ---------------- prep: w2 = 2^cw, wc = w2*centers, a2[c] = sum w2*centers^2, present=0
__global__ __launch_bounds__(128) void k_prep(const float* __restrict__ centers,
                                              const float* __restrict__ cw,
                                              float* __restrict__ w2,
                                              float* __restrict__ wc,
                                              float* __restrict__ a2,
                                              int* __restrict__ present) {
    int c = blockIdx.x;
    int t = threadIdx.x;
    float acc = 0.f;
    for (int d = t; d < D_N; d += 128) {
        float w  = exp2f(cw[c * D_N + d]);
        float ce = centers[c * D_N + d];
        float p  = w * ce;
        w2[c * D_N + d] = w;
        wc[c * D_N + d] = p;
        acc += p * ce;
    }
    for (int m = 1; m < 64; m <<= 1) acc += __shfl_xor(acc, m, 64);
    __shared__ float s[2];
    if ((t & 63) == 0) s[t >> 6] = acc;
    __syncthreads();
    if (t == 0) {
        a2[c] = s[0] + s[1];
        present[c] = 0;
    }
}

// ---------------- scatter: present[targets[i]] = 1
__global__ __launch_bounds__(256) void k_scatter(const int* __restrict__ targets,
                                                 int* __restrict__ present) {
    int i = blockIdx.x * 256 + threadIdx.x;
    if (i < B_N) present[targets[i]] = 1;
}

// ---------------- centers_dist[i] = min_{j != i} sqrt(max(sum_d w2[i,d]*(c[i,d]-c[j,d])^2, 0))
__global__ __launch_bounds__(128) void k_cdist(const float* __restrict__ centers,
                                               const float* __restrict__ w2,
                                               float* __restrict__ cdist) {
    int i = blockIdx.x;
    int j = threadIdx.x;
    float v = INFINITY;
    if (j < C_N && j != i) {
        float acc = 0.f;
        for (int d = 0; d < D_N; d++) {
            float diff = centers[i * D_N + d] - centers[j * D_N + d];
            acc = fmaf(w2[i * D_N + d] * diff, diff, acc);
        }
        v = sqrtf(fmaxf(acc, 0.f));
    }
    for (int m = 1; m < 64; m <<= 1) v = fminf(v, __shfl_xor(v, m, 64));
    __shared__ float s[2];
    if ((j & 63) == 0) s[j >> 6] = v;
    __syncthreads();
    if (j == 0) cdist[i] = fminf(s[0], s[1]);
}

// ---------------- main: per-row g(i,c) for all classes, then ap / an / loss
__global__ __launch_bounds__(256) void k_main(const float* __restrict__ inputs,
                                              const int* __restrict__ targets,
                                              const float* __restrict__ w2,
                                              const float* __restrict__ wc,
                                              const float* __restrict__ a2,
                                              const float* __restrict__ cdist,
                                              const int* __restrict__ present,
                                              float* __restrict__ partial) {
    __shared__ float xs[TILE_R * PADD];
    __shared__ float x2s[TILE_R * PADD];
    __shared__ float lsum[TILE_R];

    int tid = threadIdx.x;
    int i0 = blockIdx.x * TILE_R;

    // stage x and x^2 into LDS (float4)
    for (int q = tid; q < TILE_R * (D_N / 4); q += 256) {
        int r  = q / (D_N / 4);
        int kk = q % (D_N / 4);
        float4 v = ((const float4*)(inputs + (size_t)(i0 + r) * D_N))[kk];
        float4 v2 = make_float4(v.x * v.x, v.y * v.y, v.z * v.z, v.w * v.w);
        *(float4*)&xs[r * PADD + kk * 4]  = v;
        *(float4*)&x2s[r * PADD + kk * 4] = v2;
    }
    __syncthreads();

    int r   = tid >> 4;       // row within tile (0..15)
    int cg  = tid & 15;       // class group   (0..15)
    int row = i0 + r;
    int ti  = targets[row];

    // classes owned: c = cg + 16*cc ; nc = 7 for cg<4 else 6 (C_N = 100 = 6*16 + 4)
    const int NCMAX = 7;
    int nc = (cg < (C_N - 6 * 16)) ? 7 : 6;

    float cr[NCMAX], qd[NCMAX];
#pragma unroll
    for (int cc = 0; cc < NCMAX; cc++) { cr[cc] = 0.f; qd[cc] = 0.f; }

    for (int k = 0; k < D_N / 4; k++) {
        float4 xv  = *(const float4*)&xs[r * PADD + k * 4];
        float4 x2v = *(const float4*)&x2s[r * PADD + k * 4];
#pragma unroll
        for (int cc = 0; cc < NCMAX; cc++) {
            if (cc < nc) {
                int c = cg + (cc << 4);
                float4 a = ((const float4*)(wc + c * D_N))[k];
                float4 b = ((const float4*)(w2 + c * D_N))[k];
                cr[cc] = fmaf(xv.x,  a.x, cr[cc]);
                cr[cc] = fmaf(xv.y,  a.y, cr[cc]);
                cr[cc] = fmaf(xv.z,  a.z, cr[cc]);
                cr[cc] = fmaf(xv.w,  a.w, cr[cc]);
                qd[cc] = fmaf(x2v.x, b.x, qd[cc]);
                qd[cc] = fmaf(x2v.y, b.y, qd[cc]);
                qd[cc] = fmaf(x2v.z, b.z, qd[cc]);
                qd[cc] = fmaf(x2v.w, b.w, qd[cc]);
            }
        }
    }

    float vmin = INFINITY;   // hardest negative candidate (present classes != ti)
    float vap  = -INFINITY;  // value at c == ti
#pragma unroll
    for (int cc = 0; cc < NCMAX; cc++) {
        if (cc < nc) {
            int c = cg + (cc << 4);
            float d2 = a2[c] - 2.f * cr[cc] + qd[cc];
            float g  = sqrtf(fmaxf(d2, EPSF));
            if (c == ti) {
                vap = g;
            } else if (present[c]) {
                vmin = fminf(vmin, g);
            }
        }
    }

    // reduce across the 16 class-group lanes of this row
#pragma unroll
    for (int m = 1; m < 16; m <<= 1) {
        vmin = fminf(vmin, __shfl_xor(vmin, m, 64));
        vap  = fmaxf(vap,  __shfl_xor(vap,  m, 64));
    }

    if (cg == 0) {
        float an  = vmin;
        float ap  = vap;
        float ccv = cdist[ti];
        float loss = (an >= ccv) ? ap : (ap - an + ccv);
        lsum[r] = loss;
    }
    __syncthreads();
    if (tid == 0) {
        float s = 0.f;
#pragma unroll
        for (int rr = 0; rr < TILE_R; rr++) s += lsum[rr];
        partial[blockIdx.x] = s;
    }
}

// ---------------- final reduce of 256 block partials
__global__ __launch_bounds__(256) void k_reduce(const float* __restrict__ partial,
                                                float* __restrict__ out) {
    float v = partial[threadIdx.x];
    for (int m = 1; m < 64; m <<= 1) v += __shfl_xor(v, m, 64);
    __shared__ float s[4];
    if ((threadIdx.x & 63) == 0) s[threadIdx.x >> 6] = v;
    __syncthreads();
    if (threadIdx.x == 0) out[0] = (s[0] + s[1] + s[2] + s[3]) / (float)B_N;
}

extern "C" void kernel_launch(void* const* d_in, const int* in_sizes, int n_in,
                              void* d_out, int out_size, void* d_ws, size_t ws_size,
                              hipStream_t stream) {
    const float* inputs  = (const float*)d_in[0];
    const float* centers = (const float*)d_in[1];
    const float* cw      = (const float*)d_in[2];
    const int*   targets = (const int*)d_in[3];
    (void)in_sizes; (void)n_in; (void)out_size; (void)ws_size;

    // workspace layout (bytes)
    char* ws = (char*)d_ws;
    float* w2      = (float*)(ws + 0);                 // C*D floats
    float* wc      = (float*)(ws + 153600);            // C*D floats
    float* a2      = (float*)(ws + 307200);            // C floats
    float* cdist   = (float*)(ws + 307712);            // C floats
    int*   present = (int*)  (ws + 308224);            // C ints
    float* partial = (float*)(ws + 308736);            // 256 floats

    k_prep<<<C_N, 128, 0, stream>>>(centers, cw, w2, wc, a2, present);
    k_scatter<<<B_N / 256, 256, 0, stream>>>(targets, present);
    k_cdist<<<C_N, 128, 0, stream>>>(centers, w2, cdist);
    k_main<<<B_N / TILE_R, 256, 0, stream>>>(inputs, targets, w2, wc, a2, cdist,
                                             present, partial);
    k_reduce<<<1, 256, 0, stream>>>(partial, (float*)d_out);
}